// Round 3
// baseline (250.519 us; speedup 1.0000x reference)
//
#include <hip/hip_runtime.h>
#include <math.h>

#define Bsz 64
#define Tn 1000
#define QD 1024
#define MD 512
#define AD 128
#define NF 32
#define KS 31
#define PADc 15

#define NCH 16     // t-chunks of 64 rows (ctxc/ml granularity, k_combine contract)
#define RPC 64     // rows per chunk
#define SUB 16     // rows per MFMA subtile
#define ROWSH 520  // shorts per LDS row (512 data + 8 pad) = 1040 B

typedef __attribute__((ext_vector_type(8))) short bf16x8;
typedef __attribute__((ext_vector_type(4))) float f32x4;

// d_ws layout (bytes)
#define OFF_ENERG 32768
#define OFF_WMF  288768
#define OFF_W2F  419840
#define OFF_ML   428032
#define OFF_CTXC 436224

static __device__ __forceinline__ short f2bf(float x) {
    unsigned u = __float_as_uint(x);
    unsigned r = (u + 0x7fffu + ((u >> 16) & 1u)) >> 16;  // RNE
    return (short)r;
}
static __device__ __forceinline__ float bf2f(short s) {
    return __uint_as_float(((unsigned)(unsigned short)s) << 16);
}
static __device__ __forceinline__ float fast_tanh(float x) {
    float e2 = __expf(2.f * x);
    return 1.f - 2.f / (e2 + 1.f);
}

// ---------------------------------------------------------------------------
// Kernel A (prep, 97 blocks x 256): WmF fragment-major bf16; qsum; W2F.
// ---------------------------------------------------------------------------
__global__ __launch_bounds__(256)
void k_prep(const float* __restrict__ Wm, const float* __restrict__ conv_w,
            const float* __restrict__ conv_b, const float* __restrict__ Wloc,
            const float* __restrict__ query, const float* __restrict__ Wq,
            const float* __restrict__ bq, const float* __restrict__ bm,
            short* __restrict__ WmF, short* __restrict__ W2F,
            float* __restrict__ qsum) {
    __shared__ float qs[QD];
    __shared__ float red[256];
    int bid = blockIdx.x;
    if (bid < 32) {
        int g = bid * 256 + threadIdx.x;
        int wc = g >> 6, l = g & 63;
        int a = (wc >> 4) * 16 + (l & 15);
        int kb = (wc & 15) * 32 + (l >> 4) * 8;
        const float* src = Wm + a * MD + kb;
        float4 v0 = *(const float4*)src;
        float4 v1 = *(const float4*)(src + 4);
        bf16x8 o;
        o[0] = f2bf(v0.x); o[1] = f2bf(v0.y); o[2] = f2bf(v0.z); o[3] = f2bf(v0.w);
        o[4] = f2bf(v1.x); o[5] = f2bf(v1.y); o[6] = f2bf(v1.z); o[7] = f2bf(v1.w);
        *(bf16x8*)(WmF + (size_t)g * 8) = o;
    } else if (bid < 96) {
        int b = bid - 32;
        int a = threadIdx.x & 127;
        int half_ = threadIdx.x >> 7;
        for (int i = threadIdx.x; i < QD; i += 256) qs[i] = query[b * QD + i];
        __syncthreads();
        const float4* Wq4 = (const float4*)(Wq + a * QD + half_ * (QD / 2));
        const float4* qs4 = (const float4*)(qs + half_ * (QD / 2));
        float acc = 0.f;
#pragma unroll 4
        for (int i = 0; i < QD / 8; ++i) {
            float4 w = Wq4[i];
            float4 q = qs4[i];
            acc += w.x * q.x + w.y * q.y + w.z * q.z + w.w * q.w;
        }
        red[threadIdx.x] = acc;
        __syncthreads();
        if (half_ == 0) {
            float b2 = 0.f;
            for (int f = 0; f < NF; ++f) b2 += conv_b[f] * Wloc[a * NF + f];
            qsum[b * AD + a] = red[a] + red[a + 128] + bq[a] + bm[a] + b2;
        }
    } else {
        for (int s = threadIdx.x * 2; s < threadIdx.x * 2 + 2; ++s) {
            int w = s >> 6, l = s & 63;
            int a = w * 16 + (l & 15);
            int kb = (l >> 4) * 8;
            bf16x8 o;
#pragma unroll
            for (int j = 0; j < 8; ++j) {
                int k = kb + j;
                float sum = 0.f;
                if (k < KS)
                    for (int f = 0; f < NF; ++f) sum += conv_w[f * KS + k] * Wloc[a * NF + f];
                o[j] = f2bf(sum);  // k>=KS columns are ZERO -> no A-side guard needed
            }
            *(bf16x8*)(W2F + s * 8) = o;
        }
    }
}

// ---------------------------------------------------------------------------
// Kernel B: fused energies + ONLINE softmax/context, 2 chunks per block.
//   Grid (8,64) = 512 blocks = exactly 2/CU (one residency round). Each block
//   owns 128 rows = chunks 2*bx, 2*bx+1. Rows stream through a 2x16-row
//   double-buffered LDS subtile (35 KB total LDS). Per subtile: reg-staged
//   fp32 loads -> bf16 LDS -> 17 MFMA -> energy reduce -> online (m,l,ctx)
//   update against the resident subtile. No end-of-block softmax/ctx pass;
//   the subtile pipeline runs straight across the chunk boundary.
// ---------------------------------------------------------------------------
__global__ __launch_bounds__(512, 4)
void k_fused(const float* __restrict__ mem, const float* __restrict__ awc,
             const unsigned char* __restrict__ mask,
             const short* __restrict__ WmF, const short* __restrict__ W2F,
             const float* __restrict__ Wv, const float* __restrict__ bv,
             const float* __restrict__ qsum, float* __restrict__ energ,
             float* __restrict__ ctxc, float2* __restrict__ ml) {
    __shared__ __align__(16) short buf[2][SUB * ROWSH];  // 2 x 16640 B
    __shared__ float ered[8][SUB + 1];
    __shared__ __align__(16) float Em[SUB];
    __shared__ float vm[2 * RPC];
    __shared__ short awcsB[160];

    const int b = blockIdx.y, c2 = blockIdx.x;
    const int t0 = c2 * (2 * RPC);  // 128 rows per block
    const int tid = threadIdx.x;
    const int w = tid >> 6, lane = tid & 63, m16 = lane & 15, q = lane >> 4;

    // --- prologue staging: subtile 0 (wave w -> rows 2w, 2w+1) ---
    const float* gbase = mem + (size_t)b * Tn * MD + lane * 8;
    float4 stg[2][2][2];
#pragma unroll
    for (int rr = 0; rr < 2; ++rr) {
        int t = t0 + w * 2 + rr;
        int tc = t < Tn ? t : Tn - 1;
        const float* gp = gbase + (size_t)tc * MD;
        stg[0][rr][0] = *(const float4*)gp;
        stg[0][rr][1] = *(const float4*)(gp + 4);
    }

    // --- awc window [t0-15, t0+143] and row-validity into LDS ---
    if (tid < 160) {
        int g = t0 - PADc + tid;
        float v = (tid <= 158 && g >= 0 && g < Tn) ? awc[b * Tn + g] : 0.f;
        awcsB[tid] = f2bf(v);
    }
    if (tid < 2 * RPC) {
        int t = t0 + tid;
        vm[tid] = (t < Tn && mask[b * Tn + t] == 0) ? 1.f : 0.f;
    }

    // --- B fragments ---
    bf16x8 bfr[17];
#pragma unroll
    for (int cc = 0; cc < 16; ++cc) bfr[cc] = ((const bf16x8*)WmF)[(w * 16 + cc) * 64 + lane];
    bfr[16] = ((const bf16x8*)W2F)[w * 64 + lane];

    const int a = w * 16 + m16;
    const float wvv = Wv[a];
    const float qsv = qsum[b * AD + a];
    const float bv0 = bv[0];

    asm volatile("s_waitcnt lgkmcnt(0)" ::: "memory");
    __builtin_amdgcn_s_barrier();  // awcsB / vm visible

    float mrun = -1e30f, lrun = 0.f, ctxj = 0.f;

#pragma unroll
    for (int hf = 0; hf < 2; ++hf) {
#pragma unroll
        for (int sl = 0; sl < 4; ++sl) {
            const int ss = hf * 4 + sl;
            const int pb = ss & 1;
            // convert + write subtile-ss rows (compiler inserts exact vmcnt)
#pragma unroll
            for (int rr = 0; rr < 2; ++rr) {
                int row = w * 2 + rr;
                float4 v0 = stg[pb][rr][0];
                float4 v1 = stg[pb][rr][1];
                bf16x8 o;
                o[0] = f2bf(v0.x); o[1] = f2bf(v0.y); o[2] = f2bf(v0.z); o[3] = f2bf(v0.w);
                o[4] = f2bf(v1.x); o[5] = f2bf(v1.y); o[6] = f2bf(v1.z); o[7] = f2bf(v1.w);
                *(bf16x8*)(&buf[pb][row * ROWSH] + lane * 8) = o;
            }
            // issue subtile-(ss+1) loads; they stay in flight across barriers
            if (ss < 7) {
#pragma unroll
                for (int rr = 0; rr < 2; ++rr) {
                    int t = t0 + (ss + 1) * SUB + w * 2 + rr;
                    int tc = t < Tn ? t : Tn - 1;
                    const float* gp = gbase + (size_t)tc * MD;
                    stg[pb ^ 1][rr][0] = *(const float4*)gp;
                    stg[pb ^ 1][rr][1] = *(const float4*)(gp + 4);
                }
            }
            asm volatile("s_waitcnt lgkmcnt(0)" ::: "memory");  // ds_writes done
            __builtin_amdgcn_s_barrier();                       // subtile visible

            f32x4 acc = (f32x4){0.f, 0.f, 0.f, 0.f};
            const short* arow = &buf[pb][m16 * ROWSH + q * 8];
#pragma unroll
            for (int cc = 0; cc < 16; ++cc) {
                bf16x8 af = *(const bf16x8*)(arow + cc * 32);
                acc = __builtin_amdgcn_mfma_f32_16x16x32_bf16(af, bfr[cc], acc, 0, 0, 0);
            }
            {   // location chunk: Toeplitz window (k=31 col zeroed in W2F)
                int tl = ss * SUB + m16;
                bf16x8 af;
#pragma unroll
                for (int j = 0; j < 8; ++j) af[j] = awcsB[tl + q * 8 + j];
                acc = __builtin_amdgcn_mfma_f32_16x16x32_bf16(af, bfr[16], acc, 0, 0, 0);
            }

            // per-row energy partials: tanh, dot Wv, reduce over 16 a-lanes
#pragma unroll
            for (int r = 0; r < 4; ++r) {
                float e = wvv * fast_tanh(acc[r] + qsv);
#pragma unroll
                for (int m2 = 1; m2 < 16; m2 <<= 1) e += __shfl_xor(e, m2, 64);
                if (m16 == 0) ered[w][q * 4 + r] = e;
            }
            asm volatile("s_waitcnt lgkmcnt(0)" ::: "memory");
            __builtin_amdgcn_s_barrier();
            if (tid < SUB) {
                float E = bv0;
#pragma unroll
                for (int ww = 0; ww < 8; ++ww) E += ered[ww][tid];
                int t = t0 + ss * SUB + tid;
                if (t < Tn) energ[b * Tn + t] = E;              // raw E to global
                Em[tid] = (vm[ss * SUB + tid] != 0.f) ? E : -1e30f;  // masked
            }
            asm volatile("s_waitcnt lgkmcnt(0)" ::: "memory");
            __builtin_amdgcn_s_barrier();                        // Em visible

            // --- online softmax + context over the 16 resident rows ---
            float es[16];
            *(float4*)&es[0]  = *(const float4*)&Em[0];
            *(float4*)&es[4]  = *(const float4*)&Em[4];
            *(float4*)&es[8]  = *(const float4*)&Em[8];
            *(float4*)&es[12] = *(const float4*)&Em[12];
            float msub = es[0];
#pragma unroll
            for (int r = 1; r < 16; ++r) msub = fmaxf(msub, es[r]);
            float mnew = fmaxf(mrun, msub);
            float sc = __expf(mrun - mnew);  // both -1e30 -> 1, but l=ctx=0
            lrun *= sc;
            ctxj *= sc;
            mrun = mnew;
            if (mnew > -5e29f) {  // block-uniform branch (mnew derives from shared Em only)
#pragma unroll
                for (int r = 0; r < 16; ++r) {
                    float pr = __expf(es[r] - mnew);  // masked rows: exp(-huge)=0
                    lrun += pr;
                    ctxj += pr * bf2f(buf[pb][r * ROWSH + tid]);
                }
            }
        }
        // --- finalize chunk 2*c2+hf (contract identical to old k_fused) ---
        int c = 2 * c2 + hf;
        ctxc[((size_t)c * Bsz + b) * MD + tid] = ctxj;
        if (tid == 0) ml[c * Bsz + b] = make_float2(mrun, lrun);
        mrun = -1e30f; lrun = 0.f; ctxj = 0.f;
    }
}

// ---------------------------------------------------------------------------
// Kernel C: combine partials -> ctx, and raw energies -> wout.
// ---------------------------------------------------------------------------
__global__ __launch_bounds__(512)
void k_combine(const float* __restrict__ ctxc, const float2* __restrict__ ml,
               const float* __restrict__ energ, const unsigned char* __restrict__ mask,
               float* __restrict__ ctx, float* __restrict__ wout) {
    __shared__ float sm[NCH], sl[NCH];
    int b = blockIdx.x;
    int tid = threadIdx.x;
    if (tid < NCH) {
        float2 v = ml[tid * Bsz + b];
        sm[tid] = v.x;
        sl[tid] = v.y;
    }
    __syncthreads();
    float M = -1e30f;
#pragma unroll
    for (int cc = 0; cc < NCH; ++cc) M = fmaxf(M, sm[cc]);
    float L = 0.f;
#pragma unroll
    for (int cc = 0; cc < NCH; ++cc) L += sl[cc] * __expf(sm[cc] - M);
    float inv = 1.f / L;

    float s = 0.f;
#pragma unroll
    for (int cc = 0; cc < NCH; ++cc)
        s += ctxc[((size_t)cc * Bsz + b) * MD + tid] * __expf(sm[cc] - M);
    ctx[b * MD + tid] = s * inv;

#pragma unroll
    for (int i = 0; i < 2; ++i) {
        int t = tid + i * 512;
        if (t < Tn) {
            bool msk = mask[b * Tn + t] != 0;
            float e = energ[b * Tn + t];
            wout[b * Tn + t] = msk ? 0.f : __expf(e - M) * inv;
        }
    }
}

// ---------------------------------------------------------------------------
extern "C" void kernel_launch(void* const* d_in, const int* in_sizes, int n_in,
                              void* d_out, int out_size, void* d_ws, size_t ws_size,
                              hipStream_t stream) {
    const float* query  = (const float*)d_in[0];
    const float* memory = (const float*)d_in[1];
    const float* awc    = (const float*)d_in[2];
    const unsigned char* mask = (const unsigned char*)d_in[3];
    const float* Wq     = (const float*)d_in[4];
    const float* bq     = (const float*)d_in[5];
    const float* Wm     = (const float*)d_in[6];
    const float* bm     = (const float*)d_in[7];
    const float* Wv     = (const float*)d_in[8];
    const float* bv     = (const float*)d_in[9];
    const float* conv_w = (const float*)d_in[10];
    const float* conv_b = (const float*)d_in[11];
    const float* Wloc   = (const float*)d_in[12];

    float* out = (float*)d_out;
    float* ctx = out;             // [64,512]
    float* wout = out + Bsz * MD; // [64,1000]

    float* qsum  = (float*)d_ws;
    float* energ = (float*)((char*)d_ws + OFF_ENERG);
    short* WmF   = (short*)((char*)d_ws + OFF_WMF);
    short* W2F   = (short*)((char*)d_ws + OFF_W2F);
    float2* ml   = (float2*)((char*)d_ws + OFF_ML);
    float* ctxc  = (float*)((char*)d_ws + OFF_CTXC);

    k_prep<<<dim3(97), dim3(256), 0, stream>>>(Wm, conv_w, conv_b, Wloc, query, Wq,
                                               bq, bm, WmF, W2F, qsum);
    k_fused<<<dim3(NCH / 2, Bsz), dim3(512), 0, stream>>>(
        memory, awc, mask, WmF, W2F, Wv, bv, qsum, energ, ctxc, ml);
    k_combine<<<dim3(Bsz), dim3(512), 0, stream>>>(ctxc, ml, energ, mask, ctx, wout);
}

// Round 4
// 244.160 us; speedup vs baseline: 1.0260x; 1.0260x over previous
//
#include <hip/hip_runtime.h>
#include <math.h>

#define Bsz 64
#define Tn 1000
#define QD 1024
#define MD 512
#define AD 128
#define NF 32
#define KS 31
#define PADc 15

#define NCH 16     // t-chunks
#define RPC 64     // rows per chunk
#define SUB 16     // rows per MFMA subtile
#define ROWSH 520  // shorts per LDS row (512 data + 8 pad) = 1040 B

typedef __attribute__((ext_vector_type(8))) short bf16x8;
typedef __attribute__((ext_vector_type(4))) float f32x4;

// d_ws layout (bytes)
#define OFF_ENERG 32768
#define OFF_WMF  288768
#define OFF_W2F  419840
#define OFF_ML   428032
#define OFF_CTXC 436224

static __device__ __forceinline__ short f2bf(float x) {
    unsigned u = __float_as_uint(x);
    unsigned r = (u + 0x7fffu + ((u >> 16) & 1u)) >> 16;  // RNE
    return (short)r;
}
static __device__ __forceinline__ float bf2f(short s) {
    return __uint_as_float(((unsigned)(unsigned short)s) << 16);
}
static __device__ __forceinline__ float fast_tanh(float x) {
    float e2 = __expf(2.f * x);
    return 1.f - 2.f / (e2 + 1.f);
}

// ---------------------------------------------------------------------------
// Kernel A (prep, 97 blocks x 256): WmF fragment-major bf16; qsum; W2F.
// ---------------------------------------------------------------------------
__global__ __launch_bounds__(256)
void k_prep(const float* __restrict__ Wm, const float* __restrict__ conv_w,
            const float* __restrict__ conv_b, const float* __restrict__ Wloc,
            const float* __restrict__ query, const float* __restrict__ Wq,
            const float* __restrict__ bq, const float* __restrict__ bm,
            short* __restrict__ WmF, short* __restrict__ W2F,
            float* __restrict__ qsum) {
    __shared__ float qs[QD];
    __shared__ float red[256];
    int bid = blockIdx.x;
    if (bid < 32) {
        int g = bid * 256 + threadIdx.x;
        int wc = g >> 6, l = g & 63;
        int a = (wc >> 4) * 16 + (l & 15);
        int kb = (wc & 15) * 32 + (l >> 4) * 8;
        const float* src = Wm + a * MD + kb;
        float4 v0 = *(const float4*)src;
        float4 v1 = *(const float4*)(src + 4);
        bf16x8 o;
        o[0] = f2bf(v0.x); o[1] = f2bf(v0.y); o[2] = f2bf(v0.z); o[3] = f2bf(v0.w);
        o[4] = f2bf(v1.x); o[5] = f2bf(v1.y); o[6] = f2bf(v1.z); o[7] = f2bf(v1.w);
        *(bf16x8*)(WmF + (size_t)g * 8) = o;
    } else if (bid < 96) {
        int b = bid - 32;
        int a = threadIdx.x & 127;
        int half_ = threadIdx.x >> 7;
        for (int i = threadIdx.x; i < QD; i += 256) qs[i] = query[b * QD + i];
        __syncthreads();
        const float4* Wq4 = (const float4*)(Wq + a * QD + half_ * (QD / 2));
        const float4* qs4 = (const float4*)(qs + half_ * (QD / 2));
        float acc = 0.f;
#pragma unroll 4
        for (int i = 0; i < QD / 8; ++i) {
            float4 w = Wq4[i];
            float4 q = qs4[i];
            acc += w.x * q.x + w.y * q.y + w.z * q.z + w.w * q.w;
        }
        red[threadIdx.x] = acc;
        __syncthreads();
        if (half_ == 0) {
            float b2 = 0.f;
            for (int f = 0; f < NF; ++f) b2 += conv_b[f] * Wloc[a * NF + f];
            qsum[b * AD + a] = red[a] + red[a + 128] + bq[a] + bm[a] + b2;
        }
    } else {
        for (int s = threadIdx.x * 2; s < threadIdx.x * 2 + 2; ++s) {
            int w = s >> 6, l = s & 63;
            int a = w * 16 + (l & 15);
            int kb = (l >> 4) * 8;
            bf16x8 o;
#pragma unroll
            for (int j = 0; j < 8; ++j) {
                int k = kb + j;
                float sum = 0.f;
                if (k < KS)
                    for (int f = 0; f < NF; ++f) sum += conv_w[f * KS + k] * Wloc[a * NF + f];
                o[j] = f2bf(sum);  // k>=KS columns are ZERO -> no A-side guard needed
            }
            *(bf16x8*)(W2F + s * 8) = o;
        }
    }
}

// ---------------------------------------------------------------------------
// Kernel B: fused energies + softmax + context (R1 structure), DEPTH-2
//   staging pipeline. 512 thr = 8 waves; block owns 64 t-rows in one 66.5 KB
//   LDS chunk. Consume-then-issue: at phase s the wave first converts and
//   ds_writes stg[s&1] (subtile s), THEN issues subtile s+2's global loads
//   into the just-freed slot. In-flight window ~2 phases (>900-cyc HBM
//   latency) vs depth-1's ~1 phase -> no top-of-phase vmcnt stall. Same
//   arithmetic per element as R1 (absmax unchanged).
// ---------------------------------------------------------------------------
__global__ __launch_bounds__(512, 4)
void k_fused(const float* __restrict__ mem, const float* __restrict__ awc,
             const unsigned char* __restrict__ mask,
             const short* __restrict__ WmF, const short* __restrict__ W2F,
             const float* __restrict__ Wv, const float* __restrict__ bv,
             const float* __restrict__ qsum, float* __restrict__ energ,
             float* __restrict__ ctxc, float2* __restrict__ ml) {
    __shared__ __align__(16) short chunk[RPC * ROWSH];  // 66560 B
    __shared__ float ered[8][SUB + 1];
    __shared__ float Esub[RPC];
    __shared__ float ps[RPC];
    __shared__ float vmask[RPC];
    __shared__ short awcsB[96];

    const int b = blockIdx.y, c = blockIdx.x;
    const int t0 = c * RPC;
    const int tid = threadIdx.x;
    const int w = tid >> 6, lane = tid & 63, m16 = lane & 15, q = lane >> 4;

    // --- prologue: issue subtile 0 AND subtile 1 loads (depth-2 prime) ---
    const float* gbase = mem + (size_t)b * Tn * MD + lane * 8;
    float4 stg[2][2][2];
#pragma unroll
    for (int s = 0; s < 2; ++s) {
#pragma unroll
        for (int rr = 0; rr < 2; ++rr) {
            int t = t0 + s * SUB + w * 2 + rr;
            int tc = t < Tn ? t : Tn - 1;
            const float* gp = gbase + (size_t)tc * MD;
            stg[s][rr][0] = *(const float4*)gp;
            stg[s][rr][1] = *(const float4*)(gp + 4);
        }
    }

    // --- stage awc window [t0-15, t0+79] and row-validity into LDS ---
    if (tid < 96) {
        int g = t0 - PADc + tid;
        float v = (tid <= 94 && g >= 0 && g < Tn) ? awc[b * Tn + g] : 0.f;
        awcsB[tid] = f2bf(v);
    }
    if (tid < RPC) {
        int t = t0 + tid;
        bool valid = (t < Tn) && (mask[b * Tn + (t < Tn ? t : 0)] == 0);
        vmask[tid] = valid ? 1.f : 0.f;
    }

    // --- B fragments ---
    bf16x8 bfr[17];
#pragma unroll
    for (int cc = 0; cc < 16; ++cc) bfr[cc] = ((const bf16x8*)WmF)[(w * 16 + cc) * 64 + lane];
    bfr[16] = ((const bf16x8*)W2F)[w * 64 + lane];

    const int a = w * 16 + m16;
    const float wvv = Wv[a];
    const float qsv = qsum[b * AD + a];
    const float bv0 = bv[0];

    asm volatile("s_waitcnt lgkmcnt(0)" ::: "memory");
    __builtin_amdgcn_s_barrier();  // awcsB / vmask visible

#pragma unroll
    for (int s = 0; s < 4; ++s) {
        const int pb = s & 1;
        // consume subtile-s registers (compiler inserts exact vmcnt wait)
#pragma unroll
        for (int rr = 0; rr < 2; ++rr) {
            int row = s * SUB + w * 2 + rr;
            float4 v0 = stg[pb][rr][0];
            float4 v1 = stg[pb][rr][1];
            bf16x8 o;
            o[0] = f2bf(v0.x); o[1] = f2bf(v0.y); o[2] = f2bf(v0.z); o[3] = f2bf(v0.w);
            o[4] = f2bf(v1.x); o[5] = f2bf(v1.y); o[6] = f2bf(v1.z); o[7] = f2bf(v1.w);
            *(bf16x8*)(&chunk[row * ROWSH] + lane * 8) = o;
        }
        // THEN issue subtile-(s+2) loads into the just-freed slot; they stay
        // in flight across ~2 full phases of MFMA/reduce/barriers.
        if (s < 2) {
#pragma unroll
            for (int rr = 0; rr < 2; ++rr) {
                int t = t0 + (s + 2) * SUB + w * 2 + rr;
                int tc = t < Tn ? t : Tn - 1;
                const float* gp = gbase + (size_t)tc * MD;
                stg[pb][rr][0] = *(const float4*)gp;
                stg[pb][rr][1] = *(const float4*)(gp + 4);
            }
        }
        asm volatile("s_waitcnt lgkmcnt(0)" ::: "memory");  // ds_writes done
        __builtin_amdgcn_s_barrier();                       // subtile s visible

        f32x4 acc = (f32x4){0.f, 0.f, 0.f, 0.f};
        const short* arow = &chunk[(s * SUB + m16) * ROWSH + q * 8];
#pragma unroll
        for (int cc = 0; cc < 16; ++cc) {
            bf16x8 af = *(const bf16x8*)(arow + cc * 32);
            acc = __builtin_amdgcn_mfma_f32_16x16x32_bf16(af, bfr[cc], acc, 0, 0, 0);
        }
        {   // location chunk: Toeplitz window from LDS (k=31 col zeroed in W2F)
            int tl = s * SUB + m16;
            bf16x8 af;
#pragma unroll
            for (int j = 0; j < 8; ++j) af[j] = awcsB[tl + q * 8 + j];
            acc = __builtin_amdgcn_mfma_f32_16x16x32_bf16(af, bfr[16], acc, 0, 0, 0);
        }

        // per-row energy partials: tanh, dot Wv, reduce over 16 a-lanes
#pragma unroll
        for (int r = 0; r < 4; ++r) {
            float e = wvv * fast_tanh(acc[r] + qsv);
#pragma unroll
            for (int m2 = 1; m2 < 16; m2 <<= 1) e += __shfl_xor(e, m2, 64);
            if (m16 == 0) ered[w][q * 4 + r] = e;
        }
        asm volatile("s_waitcnt lgkmcnt(0)" ::: "memory");
        __builtin_amdgcn_s_barrier();
        if (tid < SUB) {
            float E = bv0;
#pragma unroll
            for (int ww = 0; ww < 8; ++ww) E += ered[ww][tid];
            Esub[s * SUB + tid] = E;
        }
        // ered reuse in s+1 is safe: next write happens after s+1's top barrier
    }

    asm volatile("s_waitcnt lgkmcnt(0)" ::: "memory");
    __builtin_amdgcn_s_barrier();  // Esub complete

    // --- block softmax over the 64 resident rows ---
    float mx = -1e30f;
#pragma unroll
    for (int r = 0; r < RPC; ++r) {
        float e = (vmask[r] != 0.f) ? Esub[r] : -1e30f;
        mx = fmaxf(mx, e);
    }
    if (tid < RPC) ps[tid] = vmask[tid] * __expf(Esub[tid] - mx);
    asm volatile("s_waitcnt lgkmcnt(0)" ::: "memory");
    __builtin_amdgcn_s_barrier();

    // --- context: thread j accumulates m-dim j from the LDS chunk ---
    float ctxj = 0.f, psum = 0.f;
#pragma unroll 8
    for (int r = 0; r < RPC; ++r) {
        float p = ps[r];
        psum += p;
        ctxj += p * bf2f(chunk[r * ROWSH + tid]);
    }
    ctxc[((size_t)c * Bsz + b) * MD + tid] = ctxj;
    if (tid < RPC) {
        int t = t0 + tid;
        if (t < Tn) energ[b * Tn + t] = Esub[tid];
    }
    if (tid == 0) ml[c * Bsz + b] = make_float2(mx, psum);
}

// ---------------------------------------------------------------------------
// Kernel C: combine partials -> ctx, and raw energies -> wout.
// ---------------------------------------------------------------------------
__global__ __launch_bounds__(512)
void k_combine(const float* __restrict__ ctxc, const float2* __restrict__ ml,
               const float* __restrict__ energ, const unsigned char* __restrict__ mask,
               float* __restrict__ ctx, float* __restrict__ wout) {
    __shared__ float sm[NCH], sl[NCH];
    int b = blockIdx.x;
    int tid = threadIdx.x;
    if (tid < NCH) {
        float2 v = ml[tid * Bsz + b];
        sm[tid] = v.x;
        sl[tid] = v.y;
    }
    __syncthreads();
    float M = -1e30f;
#pragma unroll
    for (int cc = 0; cc < NCH; ++cc) M = fmaxf(M, sm[cc]);
    float L = 0.f;
#pragma unroll
    for (int cc = 0; cc < NCH; ++cc) L += sl[cc] * __expf(sm[cc] - M);
    float inv = 1.f / L;

    float s = 0.f;
#pragma unroll
    for (int cc = 0; cc < NCH; ++cc)
        s += ctxc[((size_t)cc * Bsz + b) * MD + tid] * __expf(sm[cc] - M);
    ctx[b * MD + tid] = s * inv;

#pragma unroll
    for (int i = 0; i < 2; ++i) {
        int t = tid + i * 512;
        if (t < Tn) {
            bool msk = mask[b * Tn + t] != 0;
            float e = energ[b * Tn + t];
            wout[b * Tn + t] = msk ? 0.f : __expf(e - M) * inv;
        }
    }
}

// ---------------------------------------------------------------------------
extern "C" void kernel_launch(void* const* d_in, const int* in_sizes, int n_in,
                              void* d_out, int out_size, void* d_ws, size_t ws_size,
                              hipStream_t stream) {
    const float* query  = (const float*)d_in[0];
    const float* memory = (const float*)d_in[1];
    const float* awc    = (const float*)d_in[2];
    const unsigned char* mask = (const unsigned char*)d_in[3];
    const float* Wq     = (const float*)d_in[4];
    const float* bq     = (const float*)d_in[5];
    const float* Wm     = (const float*)d_in[6];
    const float* bm     = (const float*)d_in[7];
    const float* Wv     = (const float*)d_in[8];
    const float* bv     = (const float*)d_in[9];
    const float* conv_w = (const float*)d_in[10];
    const float* conv_b = (const float*)d_in[11];
    const float* Wloc   = (const float*)d_in[12];

    float* out = (float*)d_out;
    float* ctx = out;             // [64,512]
    float* wout = out + Bsz * MD; // [64,1000]

    float* qsum  = (float*)d_ws;
    float* energ = (float*)((char*)d_ws + OFF_ENERG);
    short* WmF   = (short*)((char*)d_ws + OFF_WMF);
    short* W2F   = (short*)((char*)d_ws + OFF_W2F);
    float2* ml   = (float2*)((char*)d_ws + OFF_ML);
    float* ctxc  = (float*)((char*)d_ws + OFF_CTXC);

    k_prep<<<dim3(97), dim3(256), 0, stream>>>(Wm, conv_w, conv_b, Wloc, query, Wq,
                                               bq, bm, WmF, W2F, qsum);
    k_fused<<<dim3(NCH, Bsz), dim3(512), 0, stream>>>(
        memory, awc, mask, WmF, W2F, Wv, bv, qsum, energ, ctxc, ml);
    k_combine<<<dim3(Bsz), dim3(512), 0, stream>>>(ctxc, ml, energ, mask, ctx, wout);
}